// Round 1
// baseline (1092.234 us; speedup 1.0000x reference)
//
#include <hip/hip_runtime.h>
#include <math.h>

#define PI_F 3.14159265358979323846f

__device__ __forceinline__ float sigm_(float x){ return 1.0f/(1.0f+__expf(-x)); }
__device__ __forceinline__ float silu_(float x){ return x*sigm_(x); }

// ---------------------------------------------------------------------------
// K1: precompute (tiny, 1 block / 64 threads)
//   pre[0..299]    : s1 trajectory s1^{(l)}[c]  (node-1 state entering layer l)
//   pre[300..1799] : w_bar[l][p][c]  (bar-edge path weights, constant per layer)
// ---------------------------------------------------------------------------
__global__ void precompute_kernel(const float* __restrict__ W_embed,
                                  const float* __restrict__ Wr1,
                                  const float* __restrict__ br1,
                                  const float* __restrict__ Wr2,
                                  const float* __restrict__ Ws,
                                  float* __restrict__ pre)
{
    __shared__ float s1[50];
    __shared__ float hid[64];
    const int lane = threadIdx.x;   // 64 threads

    if (lane < 50) s1[lane] = W_embed[lane] + W_embed[50 + lane];   // node_attr [1,0]
    __syncthreads();

    // bar-edge embedding: r = HALF_BAR = 0.05, edge_attr = [0,1]
    const float wdt = 0.06f / 9.0f;
    const float rbar = 0.05f;
    const float fcb = 0.5f * (__cosf(PI_F * (rbar / 0.06f)) + 1.0f);
    float emb[12];
#pragma unroll
    for (int i = 0; i < 10; ++i) {
        float d = (rbar - (float)i * wdt) / wdt;
        emb[i] = __expf(-d * d) * fcb;
    }
    emb[10] = 0.0f; emb[11] = 1.0f;

    for (int l = 0; l < 6; ++l) {
        if (lane < 50) pre[l * 50 + lane] = s1[lane];   // state BEFORE this layer's update

        // bar MLP hidden
        float a = br1[l * 64 + lane];
#pragma unroll
        for (int i = 0; i < 12; ++i) a += emb[i] * Wr1[l * 768 + i * 64 + lane];
        hid[lane] = silu_(a);
        __syncthreads();

        // w_bar = (hid @ Wr2[l]) * fcut_bar   (all 250 outputs)
        for (int m = lane; m < 250; m += 64) {
            float acc = 0.0f;
            for (int j = 0; j < 64; ++j) acc += hid[j] * Wr2[l * 16000 + j * 250 + m];
            pre[300 + l * 250 + m] = acc * fcb;
        }

        // node-1 self update: s1 <- silu(s1 @ Ws[l])   (no incoming messages)
        float sacc = 0.0f;
        if (lane < 50) {
            for (int c = 0; c < 50; ++c) sacc += s1[c] * Ws[l * 2500 + c * 50 + lane];
        }
        __syncthreads();
        if (lane < 50) s1[lane] = silu_(sacc);
        __syncthreads();
    }
}

// ---------------------------------------------------------------------------
// K2: fused forward. One wave per window (b,t). Lane k (= channel) holds
// s3,s4,s5 and v3,v4,v5 (x,y,z) in registers across all 6 layers.
// LDS: one 7800-float weight buffer reused in two phases per layer,
// plus per-wave scratch planes (h / vv broadcast + MLP hidden).
// ---------------------------------------------------------------------------
__global__ __launch_bounds__(256)
void fused_main(const float* __restrict__ y,
                const float* __restrict__ W_embed,
                const float* __restrict__ Wr1,
                const float* __restrict__ br1,
                const float* __restrict__ Wr2,
                const float* __restrict__ Ws,
                const float* __restrict__ Wv,
                const float* __restrict__ Wg,
                const float* __restrict__ W_out,
                const float* __restrict__ pre,
                float* __restrict__ out)
{
    // phase A: [0..6399] Wr2 slice (cols 0..99) as [j][100]; [6400..7167] Wr1 [i][64]; [7168..7231] br1
    // phase B: [0..2599] Ws (rows padded to 52), [2600..5199] Wg, [5200..7799] Wv
    __shared__ float ldsW[7800];
    __shared__ __attribute__((aligned(16))) float sc[4][736];
    // per-wave scratch layout (floats): h3@0, h4@56, h5@112,
    // vv3x@168, vv3y@224, vv3z@280, vv4x@336, vv4y@392, vv4z@448,
    // vv5x@504, vv5y@560, vv5z@616, hid@672(64)

    const int tid  = threadIdx.x;
    const int wave = tid >> 6;
    const int lane = tid & 63;
    const int wid  = blockIdx.x * 4 + wave;
    const int b    = wid >> 9;
    const int tw   = wid & 511;
    const int kl   = (lane < 50) ? lane : 49;   // clamp: lanes >=50 mirror lane 49 (finite), zeroed at writes

    // ---- geometry (wave-uniform values, replicated per lane) ----
    const float* yb = y + ((size_t)(b * 514 + tw)) * 6;
    float c0x = yb[0], c0y = yb[1];
    float c1x = yb[6], c1y = yb[7], a1 = yb[8];
    float sn, cs; __sincosf(a1, &sn, &cs);
    float offx = -0.05f * sn, offy = 0.05f * cs;          // off at t+1
    // spine edge (1->4): vec = ctr_t - ctr_{t+1}
    float svx = c0x - c1x, svy = c0y - c1y;
    float r_sp = sqrtf(svx * svx + svy * svy);
    float inv_sp = 1.0f / (r_sp + 1e-12f);
    float uspx = svx * inv_sp, uspy = svy * inv_sp;
    // bar edges (4->3): vec = -off ; (4->5): vec = +off
    float rb2 = sqrtf(offx * offx + offy * offy);
    float invb = 1.0f / (rb2 + 1e-12f);
    float u3x = -offx * invb, u3y = -offy * invb;
    float u5x = -u3x, u5y = -u3y;

    // spine embedding
    const float wdt = 0.06f / 9.0f;
    float tcl = fminf(fmaxf(r_sp * (1.0f / 0.06f), 0.0f), 1.0f);
    float fc_sp = 0.5f * (__cosf(PI_F * tcl) + 1.0f);
    float emb[10];
#pragma unroll
    for (int i = 0; i < 10; ++i) {
        float d = (r_sp - (float)i * wdt) / wdt;
        emb[i] = __expf(-d * d) * fc_sp;
    }

    // ---- initial state ----
    float s3 = W_embed[kl] + W_embed[100 + kl];   // node_attr [0,1]
    float s5 = s3;
    float s4 = W_embed[kl] + W_embed[50 + kl];    // node_attr [1,0]
    float v3x = 0, v3y = 0, v3z = 0, v4x = 0, v4y = 0, v4z = 0, v5x = 0, v5y = 0, v5z = 0;

    float* scw = sc[wave];
    const float4* H3q = (const float4*)(scw);
    const float4* H4q = (const float4*)(scw + 56);
    const float4* H5q = (const float4*)(scw + 112);
    const float4* Q3X = (const float4*)(scw + 168);
    const float4* Q3Y = (const float4*)(scw + 224);
    const float4* Q3Z = (const float4*)(scw + 280);
    const float4* Q4X = (const float4*)(scw + 336);
    const float4* Q4Y = (const float4*)(scw + 392);
    const float4* Q4Z = (const float4*)(scw + 448);
    const float4* Q5X = (const float4*)(scw + 504);
    const float4* Q5Y = (const float4*)(scw + 560);
    const float4* Q5Z = (const float4*)(scw + 616);

    for (int l = 0; l < 6; ++l) {
        // ======== phase A: stage Wr2 slice (paths 0,1) + Wr1 + br1 ========
        __syncthreads();
        {
            const float* wr2l = Wr2 + l * 16000;
            for (int idx = tid; idx < 6400; idx += 256) {
                int j = idx / 100;
                int m = idx - j * 100;
                ldsW[idx] = wr2l[j * 250 + m];
            }
            const float* wr1l = Wr1 + l * 768;
            for (int idx = tid; idx < 768; idx += 256) ldsW[6400 + idx] = wr1l[idx];
            if (tid < 64) ldsW[7168 + tid] = br1[l * 64 + tid];
        }
        __syncthreads();

        // per-layer small tables (L1/L2-resident)
        float s1l = pre[l * 50 + kl];
        const float* wbp = pre + 300 + l * 250;
        float wb0 = wbp[kl], wb1 = wbp[50 + kl], wb2 = wbp[100 + kl],
              wb3 = wbp[150 + kl], wb4 = wbp[200 + kl];

        // ---- spine-edge MLP (paths 0,1 only; skip when fcut==0) ----
        float wsp0 = 0.0f, wsp1 = 0.0f;
        if (fc_sp > 0.0f) {
            float a = ldsW[7168 + lane] + ldsW[6400 + 10 * 64 + lane];  // br1 + attr0*Wr1[10]
#pragma unroll
            for (int i = 0; i < 10; ++i) a += emb[i] * ldsW[6400 + i * 64 + lane];
            scw[672 + lane] = silu_(a);
            const float4* hq = (const float4*)(scw + 672);
            float a0 = 0.0f, a1w = 0.0f;
#pragma unroll
            for (int jc = 0; jc < 16; ++jc) {
                float4 hv = hq[jc];
                int jb = jc * 4;
                a0  += hv.x * ldsW[(jb    ) * 100 + kl] + hv.y * ldsW[(jb + 1) * 100 + kl]
                     + hv.z * ldsW[(jb + 2) * 100 + kl] + hv.w * ldsW[(jb + 3) * 100 + kl];
                a1w += hv.x * ldsW[(jb    ) * 100 + 50 + kl] + hv.y * ldsW[(jb + 1) * 100 + 50 + kl]
                     + hv.z * ldsW[(jb + 2) * 100 + 50 + kl] + hv.w * ldsW[(jb + 3) * 100 + 50 + kl];
            }
            wsp0 = a0 * fc_sp;
            wsp1 = a1w * fc_sp;
        }

        // ======== phase B: stage Ws / Wg / Wv (rows 50,51 zero-padded) ========
        __syncthreads();
        {
            const float* wsl = Ws + l * 2500;
            const float* wgl = Wg + l * 2500;
            const float* wvl = Wv + l * 2500;
            for (int idx = tid; idx < 2600; idx += 256) {
                bool ok = idx < 2500;
                ldsW[idx]        = ok ? wsl[idx] : 0.0f;
                ldsW[2600 + idx] = ok ? wgl[idx] : 0.0f;
                ldsW[5200 + idx] = ok ? wvl[idx] : 0.0f;
            }
        }
        __syncthreads();

        // ---- messages (lane = channel c) ----
        const float THIRD = 1.0f / 3.0f;
        float dot3 = v4x * u3x + v4y * u3y;
        float dot5 = v4x * u5x + v4y * u5y;
        float ms3 = wb0 * s4 + wb2 * dot3;
        float ms5 = wb0 * s4 + wb2 * dot5;
        float ms4 = wsp0 * s1l;
        float mv3x = wb1 * s4 * u3x + wb3 * (-v4z * u3y) + wb4 * (dot3 * u3x - v4x * THIRD);
        float mv3y = wb1 * s4 * u3y + wb3 * ( v4z * u3x) + wb4 * (dot3 * u3y - v4y * THIRD);
        float mv3z = wb3 * (v4x * u3y - v4y * u3x) + wb4 * (-v4z * THIRD);
        float mv5x = wb1 * s4 * u5x + wb3 * (-v4z * u5y) + wb4 * (dot5 * u5x - v4x * THIRD);
        float mv5y = wb1 * s4 * u5y + wb3 * ( v4z * u5x) + wb4 * (dot5 * u5y - v4y * THIRD);
        float mv5z = wb3 * (v4x * u5y - v4y * u5x) + wb4 * (-v4z * THIRD);
        float mv4x = wsp1 * s1l * uspx;
        float mv4y = wsp1 * s1l * uspy;

        float h3 = s3 + ms3, h4 = s4 + ms4, h5 = s5 + ms5;
        float vv3x = v3x + mv3x, vv3y = v3y + mv3y, vv3z = v3z + mv3z;
        float vv4x = v4x + mv4x, vv4y = v4y + mv4y, vv4z = v4z;
        float vv5x = v5x + mv5x, vv5y = v5y + mv5y, vv5z = v5z + mv5z;

        // write broadcast planes (pad entries 50,51 with zeros)
        if (lane < 52) {
            bool act = lane < 50;
            scw[      lane] = act ? h3   : 0.0f;
            scw[ 56 + lane] = act ? h4   : 0.0f;
            scw[112 + lane] = act ? h5   : 0.0f;
            scw[168 + lane] = act ? vv3x : 0.0f;
            scw[224 + lane] = act ? vv3y : 0.0f;
            scw[280 + lane] = act ? vv3z : 0.0f;
            scw[336 + lane] = act ? vv4x : 0.0f;
            scw[392 + lane] = act ? vv4y : 0.0f;
            scw[448 + lane] = act ? vv4z : 0.0f;
            scw[504 + lane] = act ? vv5x : 0.0f;
            scw[560 + lane] = act ? vv5y : 0.0f;
            scw[616 + lane] = act ? vv5z : 0.0f;
        }

        // ---- 5 fused 50x50 matmuls over c, output channel k = lane ----
        float as3 = 0, as4 = 0, as5 = 0, ag3 = 0, ag4 = 0, ag5 = 0;
        float av3x = 0, av3y = 0, av3z = 0, av4x = 0, av4y = 0, av4z = 0, av5x = 0, av5y = 0, av5z = 0;
        for (int c4 = 0; c4 < 13; ++c4) {
            float4 h3v = H3q[c4], h4v = H4q[c4], h5v = H5q[c4];
            float4 q3x = Q3X[c4], q3y = Q3Y[c4], q3z = Q3Z[c4];
            float4 q4x = Q4X[c4], q4y = Q4Y[c4], q4z = Q4Z[c4];
            float4 q5x = Q5X[c4], q5y = Q5Y[c4], q5z = Q5Z[c4];
            int cb = c4 * 4;
#define MMSTEP(comp, coff) { \
            int c = cb + coff; \
            float wsv = ldsW[c * 50 + kl]; \
            float wgv = ldsW[2600 + c * 50 + kl]; \
            float wvv = ldsW[5200 + c * 50 + kl]; \
            as3 += h3v.comp * wsv; ag3 += h3v.comp * wgv; \
            as4 += h4v.comp * wsv; ag4 += h4v.comp * wgv; \
            as5 += h5v.comp * wsv; ag5 += h5v.comp * wgv; \
            av3x += q3x.comp * wvv; av3y += q3y.comp * wvv; av3z += q3z.comp * wvv; \
            av4x += q4x.comp * wvv; av4y += q4y.comp * wvv; av4z += q4z.comp * wvv; \
            av5x += q5x.comp * wvv; av5y += q5y.comp * wvv; av5z += q5z.comp * wvv; }
            MMSTEP(x, 0) MMSTEP(y, 1) MMSTEP(z, 2) MMSTEP(w, 3)
#undef MMSTEP
        }

        // ---- epilogue: silu / gate ----
        float g3 = sigm_(ag3), g4 = sigm_(ag4), g5 = sigm_(ag5);
        s3 = silu_(as3); s4 = silu_(as4); s5 = silu_(as5);
        v3x = av3x * g3; v3y = av3y * g3; v3z = av3z * g3;
        v4x = av4x * g4; v4y = av4y * g4; v4z = av4z * g4;
        v5x = av5x * g5; v5y = av5y * g5; v5z = av5z * g5;
    }

    // ---- output: out_n = sum_c v_n[c,:] * W_out[c]; force + torque ----
    float wo = (lane < 50) ? W_out[lane] : 0.0f;
    float px  = (v3x + v4x + v5x) * wo;
    float py  = (v3y + v4y + v5y) * wo;
    float dxv = (v3x - v5x) * wo;
    float dyv = (v3y - v5y) * wo;
#pragma unroll
    for (int o = 32; o > 0; o >>= 1) {
        px  += __shfl_xor(px, o);
        py  += __shfl_xor(py, o);
        dxv += __shfl_xor(dxv, o);
        dyv += __shfl_xor(dyv, o);
    }
    if (lane == 0) {
        float* op = out + ((size_t)(b * 514 + (tw + 1))) * 3;
        op[0] = px;
        op[1] = py;
        op[2] = offx * dyv - offy * dxv;   // cross2d(off,out3) + cross2d(-off,out5)
    }
}

// ---------------------------------------------------------------------------
extern "C" void kernel_launch(void* const* d_in, const int* in_sizes, int n_in,
                              void* d_out, int out_size, void* d_ws, size_t ws_size,
                              hipStream_t stream) {
    const float* y       = (const float*)d_in[0];
    const float* W_embed = (const float*)d_in[1];
    const float* Wr1     = (const float*)d_in[2];
    const float* br1     = (const float*)d_in[3];
    const float* Wr2     = (const float*)d_in[4];
    const float* Ws      = (const float*)d_in[5];
    const float* Wv      = (const float*)d_in[6];
    const float* Wg      = (const float*)d_in[7];
    const float* W_out   = (const float*)d_in[8];
    float* out = (float*)d_out;
    float* pre = (float*)d_ws;   // 1800 floats

    hipMemsetAsync(d_out, 0, (size_t)out_size * sizeof(float), stream);
    precompute_kernel<<<1, 64, 0, stream>>>(W_embed, Wr1, br1, Wr2, Ws, pre);
    // 32768 windows, 4 waves/block, 1 window/wave
    fused_main<<<8192, 256, 0, stream>>>(y, W_embed, Wr1, br1, Wr2, Ws, Wv, Wg, W_out, pre, out);
}

// Round 2
// 543.087 us; speedup vs baseline: 2.0112x; 2.0112x over previous
//
#include <hip/hip_runtime.h>
#include <math.h>

#define PI_F 3.14159265358979323846f

typedef float v2f __attribute__((ext_vector_type(2)));
__device__ __forceinline__ v2f mkv(float a, float b){ v2f r; r.x = a; r.y = b; return r; }
__device__ __forceinline__ float sigm_(float x){ return 1.0f/(1.0f+__expf(-x)); }
__device__ __forceinline__ float silu_(float x){ return x*sigm_(x); }

// ---------------------------------------------------------------------------
// K1: precompute.
//  block 0          : pre[0..299]   s1 trajectory (node-1 state entering layer l)
//                     pre[300..1799] w_bar[l][p][c] (bar-edge weights, r=0.05 const)
//  blocks 1..6*(N+1): spine-edge weight table T[l][i][p][c], p in {0,1},
//                     r_i = i*0.06/N, value = (MLP(emb(r))@Wr2[:,p*50+c]) * fcut(r)
// ---------------------------------------------------------------------------
__global__ void precompute_kernel(const float* __restrict__ W_embed,
                                  const float* __restrict__ Wr1,
                                  const float* __restrict__ br1,
                                  const float* __restrict__ Wr2,
                                  const float* __restrict__ Ws,
                                  float* __restrict__ pre,
                                  float* __restrict__ T,
                                  int tabN)
{
    __shared__ float s1[50];
    __shared__ float hid[64];
    const int lane = threadIdx.x;   // 64 threads
    const float wdt = 0.06f / 9.0f;

    if (blockIdx.x == 0) {
        if (lane < 50) s1[lane] = W_embed[lane] + W_embed[50 + lane];   // node_attr [1,0]
        __syncthreads();

        // bar-edge embedding: r = HALF_BAR = 0.05, edge_attr = [0,1]
        const float rbar = 0.05f;
        const float fcb = 0.5f * (__cosf(PI_F * (rbar / 0.06f)) + 1.0f);
        float emb[12];
#pragma unroll
        for (int i = 0; i < 10; ++i) {
            float d = (rbar - (float)i * wdt) / wdt;
            emb[i] = __expf(-d * d) * fcb;
        }
        emb[10] = 0.0f; emb[11] = 1.0f;

        for (int l = 0; l < 6; ++l) {
            if (lane < 50) pre[l * 50 + lane] = s1[lane];

            float a = br1[l * 64 + lane];
#pragma unroll
            for (int i = 0; i < 12; ++i) a += emb[i] * Wr1[l * 768 + i * 64 + lane];
            hid[lane] = silu_(a);
            __syncthreads();

            for (int m = lane; m < 250; m += 64) {
                float acc = 0.0f;
                for (int j = 0; j < 64; ++j) acc += hid[j] * Wr2[l * 16000 + j * 250 + m];
                pre[300 + l * 250 + m] = acc * fcb;
            }

            float sacc = 0.0f;
            if (lane < 50) {
                for (int c = 0; c < 50; ++c) sacc += s1[c] * Ws[l * 2500 + c * 50 + lane];
            }
            __syncthreads();
            if (lane < 50) s1[lane] = silu_(sacc);
            __syncthreads();
        }
    } else {
        int idx = blockIdx.x - 1;
        int l = idx / (tabN + 1);
        int i = idx - l * (tabN + 1);
        float r = (float)i * (0.06f / (float)tabN);
        float t = fminf(r * (1.0f / 0.06f), 1.0f);
        float fc = 0.5f * (__cosf(PI_F * t) + 1.0f);
        float emb[10];
#pragma unroll
        for (int k = 0; k < 10; ++k) {
            float d = (r - (float)k * wdt) / wdt;
            emb[k] = __expf(-d * d) * fc;
        }
        // hidden: edge_attr = [1,0] -> add Wr1 row 10
        float a = br1[l * 64 + lane] + Wr1[l * 768 + 640 + lane];
#pragma unroll
        for (int k = 0; k < 10; ++k) a += emb[k] * Wr1[l * 768 + k * 64 + lane];
        hid[lane] = silu_(a);
        __syncthreads();
        for (int m = lane; m < 100; m += 64) {   // paths 0,1 only (v_src = 0 on spine)
            float acc = 0.0f;
            for (int j = 0; j < 64; ++j) acc += hid[j] * Wr2[l * 16000 + j * 250 + m];
            T[((size_t)(l * (tabN + 1) + i)) * 100 + m] = acc * fc;
        }
    }
}

// ---------------------------------------------------------------------------
// K2: fused forward. One wave per window. Lane = channel. Per layer:
// stage Ws/Wg/Wv (7500 floats), table-lookup spine weights, messages,
// 5 fused 50x50 matmuls with packed-fp32 accumulation.
// ---------------------------------------------------------------------------
__global__ __launch_bounds__(256, 4)
void fused_main(const float* __restrict__ y,
                const float* __restrict__ W_embed,
                const float* __restrict__ Ws,
                const float* __restrict__ Wv,
                const float* __restrict__ Wg,
                const float* __restrict__ W_out,
                const float* __restrict__ pre,
                const float* __restrict__ T,
                int tabN,
                float* __restrict__ out)
{
    // ldsW: Ws[0..2499] Wg[2500..4999] Wv[5000..7499]   (layout [c][k])
    __shared__ float ldsW[7500];
    // per-wave broadcast planes, stride 52: h3,h4,h5, q3x..q5z (12 vector planes)
    __shared__ __attribute__((aligned(16))) float sc[4][624];

    const int tid  = threadIdx.x;
    const int wave = tid >> 6;
    const int lane = tid & 63;
    const int wid  = blockIdx.x * 4 + wave;
    const int b    = wid >> 9;
    const int tw   = wid & 511;
    const int kl   = (lane < 50) ? lane : 49;

    // ---- geometry (wave-uniform, replicated) ----
    const float* yb = y + ((size_t)(b * 514 + tw)) * 6;
    float c0x = yb[0], c0y = yb[1];
    float c1x = yb[6], c1y = yb[7], a1 = yb[8];
    float sn, cs; __sincosf(a1, &sn, &cs);
    float offx = -0.05f * sn, offy = 0.05f * cs;
    float svx = c0x - c1x, svy = c0y - c1y;
    float r_sp = sqrtf(svx * svx + svy * svy);
    float inv_sp = 1.0f / (r_sp + 1e-12f);
    float uspx = svx * inv_sp, uspy = svy * inv_sp;
    float rb2 = sqrtf(offx * offx + offy * offy);
    float invb = 1.0f / (rb2 + 1e-12f);
    float u3x = -offx * invb, u3y = -offy * invb;
    float u5x = -u3x, u5y = -u3y;

    // ---- spine table coordinates (fixed across layers) ----
    float tp = r_sp * ((float)tabN / 0.06f);
    bool  inr = tp < (float)tabN;
    int   ti = (int)tp;
    if (ti > tabN - 1) ti = tabN - 1;
    if (ti < 0) ti = 0;
    float fr = tp - (float)ti;

    // ---- initial state ----
    float s3 = W_embed[kl] + W_embed[100 + kl];   // node_attr [0,1]
    float s5 = s3;
    float s4 = W_embed[kl] + W_embed[50 + kl];    // node_attr [1,0]
    float v3x = 0, v3y = 0, v3z = 0, v4x = 0, v4y = 0, v4z = 0, v5x = 0, v5y = 0, v5z = 0;

    float* scw = sc[wave];
    const float4* H3q = (const float4*)(scw);
    const float4* H4q = (const float4*)(scw + 52);
    const float4* H5q = (const float4*)(scw + 104);
    const float4* Q3X = (const float4*)(scw + 156);
    const float4* Q3Y = (const float4*)(scw + 208);
    const float4* Q3Z = (const float4*)(scw + 260);
    const float4* Q4X = (const float4*)(scw + 312);
    const float4* Q4Y = (const float4*)(scw + 364);
    const float4* Q4Z = (const float4*)(scw + 416);
    const float4* Q5X = (const float4*)(scw + 468);
    const float4* Q5Y = (const float4*)(scw + 520);
    const float4* Q5Z = (const float4*)(scw + 572);

    for (int l = 0; l < 6; ++l) {
        // ---- early per-layer global loads (L2-hot small tables) ----
        float s1l = pre[l * 50 + kl];
        const float* wbp = pre + 300 + l * 250;
        float wb0 = wbp[kl], wb1 = wbp[50 + kl], wb2 = wbp[100 + kl],
              wb3 = wbp[150 + kl], wb4 = wbp[200 + kl];
        const float* tb = T + ((size_t)(l * (tabN + 1) + ti)) * 100;
        float t00 = tb[kl], t01 = tb[50 + kl], t10 = tb[100 + kl], t11 = tb[150 + kl];
        float wsp0 = inr ? (t00 + fr * (t10 - t00)) : 0.0f;
        float wsp1 = inr ? (t01 + fr * (t11 - t01)) : 0.0f;

        // ---- stage Ws/Wg/Wv into LDS (float4 copies) ----
        __syncthreads();
        {
            const float4* g0 = (const float4*)(Ws + l * 2500);
            const float4* g1 = (const float4*)(Wg + l * 2500);
            const float4* g2 = (const float4*)(Wv + l * 2500);
            float4* l0 = (float4*)(ldsW);
            float4* l1 = (float4*)(ldsW + 2500);
            float4* l2 = (float4*)(ldsW + 5000);
            for (int i4 = tid; i4 < 625; i4 += 256) {
                l0[i4] = g0[i4];
                l1[i4] = g1[i4];
                l2[i4] = g2[i4];
            }
        }
        __syncthreads();

        // ---- messages (lane = channel) ----
        const float THIRD = 1.0f / 3.0f;
        float dot3 = v4x * u3x + v4y * u3y;
        float dot5 = v4x * u5x + v4y * u5y;
        float ms3 = wb0 * s4 + wb2 * dot3;
        float ms5 = wb0 * s4 + wb2 * dot5;
        float ms4 = wsp0 * s1l;
        float mv3x = wb1 * s4 * u3x + wb3 * (-v4z * u3y) + wb4 * (dot3 * u3x - v4x * THIRD);
        float mv3y = wb1 * s4 * u3y + wb3 * ( v4z * u3x) + wb4 * (dot3 * u3y - v4y * THIRD);
        float mv3z = wb3 * (v4x * u3y - v4y * u3x) + wb4 * (-v4z * THIRD);
        float mv5x = wb1 * s4 * u5x + wb3 * (-v4z * u5y) + wb4 * (dot5 * u5x - v4x * THIRD);
        float mv5y = wb1 * s4 * u5y + wb3 * ( v4z * u5x) + wb4 * (dot5 * u5y - v4y * THIRD);
        float mv5z = wb3 * (v4x * u5y - v4y * u5x) + wb4 * (-v4z * THIRD);
        float mv4x = wsp1 * s1l * uspx;
        float mv4y = wsp1 * s1l * uspy;

        float h3 = s3 + ms3, h4 = s4 + ms4, h5 = s5 + ms5;

        if (lane < 50) {
            scw[      lane] = h3;
            scw[ 52 + lane] = h4;
            scw[104 + lane] = h5;
            scw[156 + lane] = v3x + mv3x;
            scw[208 + lane] = v3y + mv3y;
            scw[260 + lane] = v3z + mv3z;
            scw[312 + lane] = v4x + mv4x;
            scw[364 + lane] = v4y + mv4y;
            scw[416 + lane] = v4z;
            scw[468 + lane] = v5x + mv5x;
            scw[520 + lane] = v5y + mv5y;
            scw[572 + lane] = v5z + mv5z;
        }

        // ---- 5 fused 50x50 matmuls, packed fp32 pairs over c ----
        v2f as3 = {0,0}, as4 = {0,0}, as5 = {0,0};
        v2f ag3 = {0,0}, ag4 = {0,0}, ag5 = {0,0};
        v2f av3x = {0,0}, av3y = {0,0}, av3z = {0,0};
        v2f av4x = {0,0}, av4y = {0,0}, av4z = {0,0};
        v2f av5x = {0,0}, av5y = {0,0}, av5z = {0,0};

#define PAIRSTEP(HX, HY, WS_, WG_, WV_) { v2f hp;                              \
        hp = mkv(h3v.HX, h3v.HY);  as3  += hp * WS_;  ag3  += hp * WG_;        \
        hp = mkv(h4v.HX, h4v.HY);  as4  += hp * WS_;  ag4  += hp * WG_;        \
        hp = mkv(h5v.HX, h5v.HY);  as5  += hp * WS_;  ag5  += hp * WG_;        \
        hp = mkv(q3xv.HX, q3xv.HY); av3x += hp * WV_;                          \
        hp = mkv(q3yv.HX, q3yv.HY); av3y += hp * WV_;                          \
        hp = mkv(q3zv.HX, q3zv.HY); av3z += hp * WV_;                          \
        hp = mkv(q4xv.HX, q4xv.HY); av4x += hp * WV_;                          \
        hp = mkv(q4yv.HX, q4yv.HY); av4y += hp * WV_;                          \
        hp = mkv(q4zv.HX, q4zv.HY); av4z += hp * WV_;                          \
        hp = mkv(q5xv.HX, q5xv.HY); av5x += hp * WV_;                          \
        hp = mkv(q5yv.HX, q5yv.HY); av5y += hp * WV_;                          \
        hp = mkv(q5zv.HX, q5zv.HY); av5z += hp * WV_; }

        for (int c4 = 0; c4 < 12; ++c4) {
            float4 h3v = H3q[c4], h4v = H4q[c4], h5v = H5q[c4];
            float4 q3xv = Q3X[c4], q3yv = Q3Y[c4], q3zv = Q3Z[c4];
            float4 q4xv = Q4X[c4], q4yv = Q4Y[c4], q4zv = Q4Z[c4];
            float4 q5xv = Q5X[c4], q5yv = Q5Y[c4], q5zv = Q5Z[c4];
            const float* wp = ldsW + (c4 * 4) * 50 + kl;
            v2f wsA = mkv(wp[0],    wp[50]);
            v2f wgA = mkv(wp[2500], wp[2550]);
            v2f wvA = mkv(wp[5000], wp[5050]);
            PAIRSTEP(x, y, wsA, wgA, wvA)
            v2f wsB = mkv(wp[100],  wp[150]);
            v2f wgB = mkv(wp[2600], wp[2650]);
            v2f wvB = mkv(wp[5100], wp[5150]);
            PAIRSTEP(z, w, wsB, wgB, wvB)
        }
        // tail pair: channels 48,49
        {
            const float* wp = ldsW + 2400 + kl;
            v2f wsA = mkv(wp[0],    wp[50]);
            v2f wgA = mkv(wp[2500], wp[2550]);
            v2f wvA = mkv(wp[5000], wp[5050]);
            v2f hp;
            hp = *(const v2f*)(scw +  48); as3  += hp * wsA; ag3 += hp * wgA;
            hp = *(const v2f*)(scw + 100); as4  += hp * wsA; ag4 += hp * wgA;
            hp = *(const v2f*)(scw + 152); as5  += hp * wsA; ag5 += hp * wgA;
            hp = *(const v2f*)(scw + 204); av3x += hp * wvA;
            hp = *(const v2f*)(scw + 256); av3y += hp * wvA;
            hp = *(const v2f*)(scw + 308); av3z += hp * wvA;
            hp = *(const v2f*)(scw + 360); av4x += hp * wvA;
            hp = *(const v2f*)(scw + 412); av4y += hp * wvA;
            hp = *(const v2f*)(scw + 464); av4z += hp * wvA;
            hp = *(const v2f*)(scw + 516); av5x += hp * wvA;
            hp = *(const v2f*)(scw + 568); av5y += hp * wvA;
            hp = *(const v2f*)(scw + 620); av5z += hp * wvA;
        }
#undef PAIRSTEP

        // ---- epilogue ----
        float g3 = sigm_(ag3.x + ag3.y);
        float g4 = sigm_(ag4.x + ag4.y);
        float g5 = sigm_(ag5.x + ag5.y);
        s3 = silu_(as3.x + as3.y);
        s4 = silu_(as4.x + as4.y);
        s5 = silu_(as5.x + as5.y);
        v3x = (av3x.x + av3x.y) * g3; v3y = (av3y.x + av3y.y) * g3; v3z = (av3z.x + av3z.y) * g3;
        v4x = (av4x.x + av4x.y) * g4; v4y = (av4y.x + av4y.y) * g4; v4z = (av4z.x + av4z.y) * g4;
        v5x = (av5x.x + av5x.y) * g5; v5y = (av5y.x + av5y.y) * g5; v5z = (av5z.x + av5z.y) * g5;
    }

    // ---- output ----
    float wo = (lane < 50) ? W_out[lane] : 0.0f;
    float px  = (v3x + v4x + v5x) * wo;
    float py  = (v3y + v4y + v5y) * wo;
    float dxv = (v3x - v5x) * wo;
    float dyv = (v3y - v5y) * wo;
#pragma unroll
    for (int o = 32; o > 0; o >>= 1) {
        px  += __shfl_xor(px, o);
        py  += __shfl_xor(py, o);
        dxv += __shfl_xor(dxv, o);
        dyv += __shfl_xor(dyv, o);
    }
    if (lane == 0) {
        float* op = out + ((size_t)(b * 514 + (tw + 1))) * 3;
        op[0] = px;
        op[1] = py;
        op[2] = offx * dyv - offy * dxv;
    }
}

// ---------------------------------------------------------------------------
extern "C" void kernel_launch(void* const* d_in, const int* in_sizes, int n_in,
                              void* d_out, int out_size, void* d_ws, size_t ws_size,
                              hipStream_t stream) {
    const float* y       = (const float*)d_in[0];
    const float* W_embed = (const float*)d_in[1];
    const float* Wr1     = (const float*)d_in[2];
    const float* br1     = (const float*)d_in[3];
    const float* Wr2     = (const float*)d_in[4];
    const float* Ws      = (const float*)d_in[5];
    const float* Wv      = (const float*)d_in[6];
    const float* Wg      = (const float*)d_in[7];
    const float* W_out   = (const float*)d_in[8];
    float* out = (float*)d_out;
    float* pre = (float*)d_ws;            // 1800 floats
    float* T   = (float*)d_ws + 1800;     // 6*(tabN+1)*100 floats

    // pick largest table resolution that fits the workspace
    int tabN = 2048;
    while (tabN > 64 &&
           (size_t)(1800 + 6 * (tabN + 1) * 100) * sizeof(float) > ws_size)
        tabN >>= 1;

    hipMemsetAsync(d_out, 0, (size_t)out_size * sizeof(float), stream);
    precompute_kernel<<<1 + 6 * (tabN + 1), 64, 0, stream>>>(
        W_embed, Wr1, br1, Wr2, Ws, pre, T, tabN);
    fused_main<<<8192, 256, 0, stream>>>(y, W_embed, Ws, Wv, Wg, W_out, pre, T, tabN, out);
}

// Round 3
// 378.915 us; speedup vs baseline: 2.8825x; 1.4333x over previous
//
#include <hip/hip_runtime.h>
#include <math.h>

#define PI_F 3.14159265358979323846f

typedef _Float16 h8 __attribute__((ext_vector_type(8)));
typedef float f4 __attribute__((ext_vector_type(4)));

__device__ __forceinline__ float sigm_(float x){ return 1.0f/(1.0f+__expf(-x)); }
__device__ __forceinline__ float silu_(float x){ return x*sigm_(x); }
__device__ __forceinline__ h8 ldh8(const _Float16* p){
    return __builtin_bit_cast(h8, *(const float4*)(p));
}

// B layout (fp16, in d_ws):
//   B1T: per layer [n<112][k<192]  (n<50: Ws col, 50..99: Wg col, 100+: 0)
//   B2T: per layer [n<64][k<192]   (n<50: Wv col, else 0)
//   k segments: [0,50): W_hi(c=k) | [64,114): W_hi(c=k-64) | [128,178): W_lo(c=k-128), else 0
#define B1_PER_L 21504      // 112*192
#define B2_PER_L 12288      // 64*192
#define B1_TOT   129024     // 6*B1_PER_L
#define B_TOT    202752     // B1_TOT + 6*B2_PER_L

// ---------------------------------------------------------------------------
// K1a: pre[] — s1 trajectory + bar-edge weights (1 block / 64 thr). Same as R2.
// ---------------------------------------------------------------------------
__global__ void precompute_pre(const float* __restrict__ W_embed,
                               const float* __restrict__ Wr1,
                               const float* __restrict__ br1,
                               const float* __restrict__ Wr2,
                               const float* __restrict__ Ws,
                               float* __restrict__ pre)
{
    __shared__ float s1[50];
    __shared__ float hid[64];
    const int lane = threadIdx.x;
    const float wdt = 0.06f / 9.0f;

    if (lane < 50) s1[lane] = W_embed[lane] + W_embed[50 + lane];
    __syncthreads();

    const float rbar = 0.05f;
    const float fcb = 0.5f * (__cosf(PI_F * (rbar / 0.06f)) + 1.0f);
    float emb[12];
#pragma unroll
    for (int i = 0; i < 10; ++i) {
        float d = (rbar - (float)i * wdt) / wdt;
        emb[i] = __expf(-d * d) * fcb;
    }
    emb[10] = 0.0f; emb[11] = 1.0f;

    for (int l = 0; l < 6; ++l) {
        if (lane < 50) pre[l * 50 + lane] = s1[lane];
        float a = br1[l * 64 + lane];
#pragma unroll
        for (int i = 0; i < 12; ++i) a += emb[i] * Wr1[l * 768 + i * 64 + lane];
        hid[lane] = silu_(a);
        __syncthreads();
        for (int m = lane; m < 250; m += 64) {
            float acc = 0.0f;
            for (int j = 0; j < 64; ++j) acc += hid[j] * Wr2[l * 16000 + j * 250 + m];
            pre[300 + l * 250 + m] = acc * fcb;
        }
        float sacc = 0.0f;
        if (lane < 50) {
            for (int c = 0; c < 50; ++c) sacc += s1[c] * Ws[l * 2500 + c * 50 + lane];
        }
        __syncthreads();
        if (lane < 50) s1[lane] = silu_(sacc);
        __syncthreads();
    }
}

// ---------------------------------------------------------------------------
// K1b: spine-edge table, one entry per wave (shuffle-based, no LDS/barriers)
// ---------------------------------------------------------------------------
__global__ void precompute_table(const float* __restrict__ Wr1,
                                 const float* __restrict__ br1,
                                 const float* __restrict__ Wr2,
                                 float* __restrict__ T,
                                 int tabN)
{
    const int e = blockIdx.x * 4 + (threadIdx.x >> 6);
    const int lane = threadIdx.x & 63;
    const int total = 6 * (tabN + 1);
    if (e >= total) return;
    const int l = e / (tabN + 1);
    const int i = e - l * (tabN + 1);
    const float wdt = 0.06f / 9.0f;

    float r = (float)i * (0.06f / (float)tabN);
    float t = fminf(r * (1.0f / 0.06f), 1.0f);
    float fc = 0.5f * (__cosf(PI_F * t) + 1.0f);
    float emb[10];
#pragma unroll
    for (int k = 0; k < 10; ++k) {
        float d = (r - (float)k * wdt) / wdt;
        emb[k] = __expf(-d * d) * fc;
    }
    float a = br1[l * 64 + lane] + Wr1[l * 768 + 640 + lane];  // edge_attr [1,0]
#pragma unroll
    for (int k = 0; k < 10; ++k) a += emb[k] * Wr1[l * 768 + k * 64 + lane];
    float hv = silu_(a);

    float acc0 = 0.0f, acc1 = 0.0f;
    const float* wr2 = Wr2 + l * 16000;
    for (int j = 0; j < 64; ++j) {
        float hj = __shfl(hv, j);
        acc0 += hj * wr2[j * 250 + lane];
        acc1 += hj * wr2[j * 250 + 64 + lane];   // lane<36 valid; else scratch
    }
    float* tp = T + (size_t)e * 100;
    tp[lane] = acc0 * fc;               // m = 0..63
    if (lane < 36) tp[64 + lane] = acc1 * fc;   // m = 64..99
}

// ---------------------------------------------------------------------------
// K1c: build fp16 B matrices in workspace
// ---------------------------------------------------------------------------
__global__ void fill_B(const float* __restrict__ Ws,
                       const float* __restrict__ Wg,
                       const float* __restrict__ Wv,
                       _Float16* __restrict__ B)
{
    int idx = blockIdx.x * 256 + threadIdx.x;
    if (idx >= B_TOT) return;
    int l, n, k, which;
    size_t off;
    if (idx < B1_TOT) {
        l = idx / B1_PER_L; int r = idx - l * B1_PER_L;
        n = r / 192; k = r - n * 192; which = 0;
        off = (size_t)l * B1_PER_L + n * 192 + k;
    } else {
        int j = idx - B1_TOT;
        l = j / B2_PER_L; int r = j - l * B2_PER_L;
        n = r / 192; k = r - n * 192; which = 1;
        off = B1_TOT + (size_t)l * B2_PER_L + n * 192 + k;
    }
    int seg = -1, c = 0;
    if (k < 50)                 { seg = 0; c = k; }
    else if (k >= 64 && k < 114){ seg = 1; c = k - 64; }
    else if (k >= 128 && k < 178){ seg = 2; c = k - 128; }
    _Float16 val = (_Float16)0.0f;
    if (seg >= 0) {
        float w = 0.0f;
        if (which == 0) {
            if (n < 50)       w = Ws[l * 2500 + c * 50 + n];
            else if (n < 100) w = Wg[l * 2500 + c * 50 + (n - 50)];
        } else {
            if (n < 50)       w = Wv[l * 2500 + c * 50 + n];
        }
        _Float16 hi = (_Float16)w;
        val = (seg < 2) ? hi : (_Float16)(w - (float)hi);
    }
    B[off] = val;
}

// ---------------------------------------------------------------------------
// K2: fused forward. Block = 8 windows (2 per wave). Per layer:
//   A-write (fp16 hi/lo, LDS) -> MFMA (A from LDS, B from global/L2)
//   -> C into overlay region -> per-lane readback + activations.
// A: 112 rows x 144 halves (rows 0..23 H used, 24..31 pad; 32..103 Q, 104..111 pad)
// overlay: outH [100][36] f32 (words 0..3599), outQ [50][84] f32 (3600..7799)
// ---------------------------------------------------------------------------
__global__ __launch_bounds__(256, 3)
void fused_main(const float* __restrict__ y,
                const float* __restrict__ W_embed,
                const float* __restrict__ W_out,
                const float* __restrict__ pre,
                const float* __restrict__ T,
                int tabN,
                const _Float16* __restrict__ Bws,
                float* __restrict__ out)
{
    __shared__ __align__(16) char LB[112 * 144 * 2];   // 32256 B
    _Float16* A  = (_Float16*)LB;
    float* outH  = (float*)LB;          // stride 36
    float* outQ  = (float*)LB + 3600;   // stride 84

    const int tid  = threadIdx.x;
    const int wave = tid >> 6;
    const int lane = tid & 63;
    const int kl   = (lane < 50) ? lane : 49;
    const int fm   = lane & 15;
    const int fq   = lane >> 4;

    const _Float16* B1 = Bws;
    const _Float16* B2 = Bws + B1_TOT;

    // ---- per-window geometry ----
    float offx[2], offy[2], u3x_[2], u3y_[2], uspx_[2], uspy_[2], fr_[2];
    int   ti_[2], inr_[2];
#pragma unroll
    for (int w = 0; w < 2; ++w) {
        int wid = blockIdx.x * 8 + wave * 2 + w;
        int b = wid >> 9, tw = wid & 511;
        const float* yb = y + ((size_t)(b * 514 + tw)) * 6;
        float c0x = yb[0], c0y = yb[1];
        float c1x = yb[6], c1y = yb[7], a1 = yb[8];
        float sn, cs; __sincosf(a1, &sn, &cs);
        offx[w] = -0.05f * sn; offy[w] = 0.05f * cs;
        float svx = c0x - c1x, svy = c0y - c1y;
        float r_sp = sqrtf(svx * svx + svy * svy);
        float inv_sp = 1.0f / (r_sp + 1e-12f);
        uspx_[w] = svx * inv_sp; uspy_[w] = svy * inv_sp;
        float rb2 = sqrtf(offx[w] * offx[w] + offy[w] * offy[w]);
        float invb = 1.0f / (rb2 + 1e-12f);
        u3x_[w] = -offx[w] * invb; u3y_[w] = -offy[w] * invb;
        float tp = r_sp * ((float)tabN / 0.06f);
        inr_[w] = tp < (float)tabN;
        int ti = (int)tp;
        if (ti > tabN - 1) ti = tabN - 1;
        if (ti < 0) ti = 0;
        ti_[w] = ti; fr_[w] = tp - (float)ti;
    }

    // ---- initial states ----
    float s3[2], s4[2], s5[2];
    float v3x[2], v3y[2], v3z[2], v4x[2], v4y[2], v4z[2], v5x[2], v5y[2], v5z[2];
    {
        float i35 = W_embed[kl] + W_embed[100 + kl];
        float i4  = W_embed[kl] + W_embed[50 + kl];
#pragma unroll
        for (int w = 0; w < 2; ++w) {
            s3[w] = i35; s5[w] = i35; s4[w] = i4;
            v3x[w] = v3y[w] = v3z[w] = 0.0f;
            v4x[w] = v4y[w] = v4z[w] = 0.0f;
            v5x[w] = v5y[w] = v5z[w] = 0.0f;
        }
    }

    for (int l = 0; l < 6; ++l) {
        __syncthreads();   // overlay region free (prev readback done)

        // ---- per-layer channel tables (window-independent) ----
        float s1l = pre[l * 50 + kl];
        const float* wbp = pre + 300 + l * 250;
        float wb0 = wbp[kl], wb1 = wbp[50 + kl], wb2 = wbp[100 + kl],
              wb3 = wbp[150 + kl], wb4 = wbp[200 + kl];

        // ---- messages + A-writes ----
        const float THIRD = 1.0f / 3.0f;
#pragma unroll
        for (int w = 0; w < 2; ++w) {
            const float* tb = T + ((size_t)(l * (tabN + 1) + ti_[w])) * 100;
            float t00 = tb[kl], t01 = tb[50 + kl], t10 = tb[100 + kl], t11 = tb[150 + kl];
            float wsp0 = inr_[w] ? (t00 + fr_[w] * (t10 - t00)) : 0.0f;
            float wsp1 = inr_[w] ? (t01 + fr_[w] * (t11 - t01)) : 0.0f;

            float u3x = u3x_[w], u3y = u3y_[w];
            float dot3 = v4x[w] * u3x + v4y[w] * u3y;
            float ms3 = wb0 * s4[w] + wb2 * dot3;
            float ms5 = wb0 * s4[w] - wb2 * dot3;
            float ms4 = wsp0 * s1l;
            float bAx = wb1 * s4[w] * u3x - wb3 * v4z[w] * u3y;   // odd part (flips for node5)
            float bAy = wb1 * s4[w] * u3y + wb3 * v4z[w] * u3x;
            float bBx = wb4 * (dot3 * u3x - v4x[w] * THIRD);       // even part
            float bBy = wb4 * (dot3 * u3y - v4y[w] * THIRD);
            float mz3 = wb3 * (v4x[w] * u3y - v4y[w] * u3x) - wb4 * v4z[w] * THIRD;
            float mz5 = -wb3 * (v4x[w] * u3y - v4y[w] * u3x) - wb4 * v4z[w] * THIRD;

            float vals[12];
            vals[0] = s3[w] + ms3;                       // h3
            vals[1] = s4[w] + ms4;                       // h4
            vals[2] = s5[w] + ms5;                       // h5
            vals[3] = v3x[w] + bAx + bBx;                // q3x
            vals[4] = v3y[w] + bAy + bBy;                // q3y
            vals[5] = v3z[w] + mz3;                      // q3z
            vals[6] = v4x[w] + wsp1 * s1l * uspx_[w];    // q4x
            vals[7] = v4y[w] + wsp1 * s1l * uspy_[w];    // q4y
            vals[8] = v4z[w];                            // q4z
            vals[9]  = v5x[w] - bAx + bBx;               // q5x
            vals[10] = v5y[w] - bAy + bBy;               // q5y
            vals[11] = v5z[w] + mz5;                     // q5z

            int wv = wave * 2 + w;
#pragma unroll
            for (int q = 0; q < 12; ++q) {
                int row = (q < 3) ? (wv * 3 + q) : (32 + wv * 9 + (q - 3));
                float x = (lane < 50) ? vals[q] : 0.0f;
                _Float16 hi = (_Float16)x;
                _Float16 lo = (_Float16)(x - (float)hi);
                A[row * 144 + lane]      = hi;
                A[row * 144 + 64 + lane] = lo;
            }
        }
        // zero pad rows (H 24..31, Q 104..111): one b128 of zeros per thread
        {
            int pr  = tid >> 4;
            int row = (pr < 8) ? (24 + pr) : (96 + pr);
            f4 z = {0.0f, 0.0f, 0.0f, 0.0f};
            *(f4*)(A + row * 144 + (tid & 15) * 8) = z;
        }
        __syncthreads();   // A complete

        // ---- MFMA phase: jobs per wave: (H, wave), (H, 4+wave if wave<3), (Q, wave)
        f4 cst[9];
        const _Float16* B1l = B1 + (size_t)l * B1_PER_L;
        const _Float16* B2l = B2 + (size_t)l * B2_PER_L;
#pragma unroll
        for (int ji = 0; ji < 3; ++ji) {
            const bool isQ = (ji == 2);
            const bool active = !(ji == 1 && wave == 3);
            if (active) {
                int ntj = (ji == 1) ? (4 + wave) : wave;
                const _Float16* bp = (isQ ? B2l : B1l) + (ntj * 16 + fm) * 192 + fq * 8;
                h8 b0 = ldh8(bp);
                h8 b1 = ldh8(bp + 32);
                h8 b2 = ldh8(bp + 64);
                h8 b3 = ldh8(bp + 96);
                h8 b4 = ldh8(bp + 128);
                h8 b5 = ldh8(bp + 160);
#pragma unroll
                for (int mt = 0; mt < 5; ++mt) {
                    if (mt < (isQ ? 5 : 2)) {
                        int rowbase = (isQ ? 32 : 0) + mt * 16;
                        const _Float16* ap = A + (rowbase + fm) * 144 + fq * 8;
                        h8 a0 = ldh8(ap);
                        h8 a1 = ldh8(ap + 32);
                        h8 a2 = ldh8(ap + 64);
                        h8 a3 = ldh8(ap + 96);
                        f4 acc = {0.0f, 0.0f, 0.0f, 0.0f};
                        acc = __builtin_amdgcn_mfma_f32_16x16x32_f16(a0, b0, acc, 0, 0, 0);
                        acc = __builtin_amdgcn_mfma_f32_16x16x32_f16(a1, b1, acc, 0, 0, 0);
                        acc = __builtin_amdgcn_mfma_f32_16x16x32_f16(a2, b2, acc, 0, 0, 0);
                        acc = __builtin_amdgcn_mfma_f32_16x16x32_f16(a3, b3, acc, 0, 0, 0);
                        acc = __builtin_amdgcn_mfma_f32_16x16x32_f16(a0, b4, acc, 0, 0, 0);
                        acc = __builtin_amdgcn_mfma_f32_16x16x32_f16(a1, b5, acc, 0, 0, 0);
                        int slot = (ji == 0) ? mt : (ji == 1) ? 2 + mt : 4 + mt;
                        cst[slot] = acc;
                    }
                }
            }
        }
        __syncthreads();   // all A-reads done -> overlay safe

        // ---- C writes into overlay ----
#pragma unroll
        for (int ji = 0; ji < 3; ++ji) {
            const bool isQ = (ji == 2);
            const bool active = !(ji == 1 && wave == 3);
            if (active) {
                int ntj = (ji == 1) ? (4 + wave) : wave;
                int n = ntj * 16 + fm;
#pragma unroll
                for (int mt = 0; mt < 5; ++mt) {
                    if (mt < (isQ ? 5 : 2)) {
                        int m = mt * 16 + fq * 4;
                        int slot = (ji == 0) ? mt : (ji == 1) ? 2 + mt : 4 + mt;
                        if (!isQ) { if (n < 100) *(f4*)(outH + n * 36 + m) = cst[slot]; }
                        else      { if (n < 50)  *(f4*)(outQ + n * 84 + m) = cst[slot]; }
                    }
                }
            }
        }
        __syncthreads();   // outputs ready

        // ---- readback + activations ----
#pragma unroll
        for (int w = 0; w < 2; ++w) {
            int wv = wave * 2 + w;
            int mb = wv * 3, qb = wv * 9;
            float as3 = outH[kl * 36 + mb],        as4 = outH[kl * 36 + mb + 1],        as5 = outH[kl * 36 + mb + 2];
            float ag3 = outH[(50 + kl) * 36 + mb], ag4 = outH[(50 + kl) * 36 + mb + 1], ag5 = outH[(50 + kl) * 36 + mb + 2];
            float g3 = sigm_(ag3), g4 = sigm_(ag4), g5 = sigm_(ag5);
            s3[w] = silu_(as3); s4[w] = silu_(as4); s5[w] = silu_(as5);
            const float* qp = outQ + kl * 84 + qb;
            v3x[w] = qp[0] * g3; v3y[w] = qp[1] * g3; v3z[w] = qp[2] * g3;
            v4x[w] = qp[3] * g4; v4y[w] = qp[4] * g4; v4z[w] = qp[5] * g4;
            v5x[w] = qp[6] * g5; v5y[w] = qp[7] * g5; v5z[w] = qp[8] * g5;
        }
    }

    // ---- output epilogue ----
    float wo = (lane < 50) ? W_out[lane] : 0.0f;
#pragma unroll
    for (int w = 0; w < 2; ++w) {
        float px  = (v3x[w] + v4x[w] + v5x[w]) * wo;
        float py  = (v3y[w] + v4y[w] + v5y[w]) * wo;
        float dxv = (v3x[w] - v5x[w]) * wo;
        float dyv = (v3y[w] - v5y[w]) * wo;
#pragma unroll
        for (int o = 32; o > 0; o >>= 1) {
            px  += __shfl_xor(px, o);
            py  += __shfl_xor(py, o);
            dxv += __shfl_xor(dxv, o);
            dyv += __shfl_xor(dyv, o);
        }
        if (lane == 0) {
            int wid = blockIdx.x * 8 + wave * 2 + w;
            int b = wid >> 9, tw = wid & 511;
            float* op = out + ((size_t)(b * 514 + (tw + 1))) * 3;
            op[0] = px;
            op[1] = py;
            op[2] = offx[w] * dyv - offy[w] * dxv;
        }
    }
}

// ---------------------------------------------------------------------------
extern "C" void kernel_launch(void* const* d_in, const int* in_sizes, int n_in,
                              void* d_out, int out_size, void* d_ws, size_t ws_size,
                              hipStream_t stream) {
    const float* y       = (const float*)d_in[0];
    const float* W_embed = (const float*)d_in[1];
    const float* Wr1     = (const float*)d_in[2];
    const float* br1     = (const float*)d_in[3];
    const float* Wr2     = (const float*)d_in[4];
    const float* Ws      = (const float*)d_in[5];
    const float* Wv      = (const float*)d_in[6];
    const float* Wg      = (const float*)d_in[7];
    const float* W_out   = (const float*)d_in[8];
    float* out = (float*)d_out;

    _Float16* Bws = (_Float16*)d_ws;                         // 405504 B
    float* pre = (float*)((char*)d_ws + B_TOT * 2);          // 1800 floats
    float* T   = pre + 1800;

    int tabN = 2048;
    while (tabN > 64 &&
           (size_t)B_TOT * 2 + (size_t)(1800 + 6 * (tabN + 1) * 100) * sizeof(float) > ws_size)
        tabN >>= 1;

    hipMemsetAsync(d_out, 0, (size_t)out_size * sizeof(float), stream);
    precompute_pre<<<1, 64, 0, stream>>>(W_embed, Wr1, br1, Wr2, Ws, pre);
    precompute_table<<<(6 * (tabN + 1) + 3) / 4, 256, 0, stream>>>(Wr1, br1, Wr2, T, tabN);
    fill_B<<<(B_TOT + 255) / 256, 256, 0, stream>>>(Ws, Wg, Wv, Bws);
    fused_main<<<4096, 256, 0, stream>>>(y, W_embed, W_out, pre, T, tabN, Bws, out);
}

// Round 4
// 300.359 us; speedup vs baseline: 3.6364x; 1.2615x over previous
//
#include <hip/hip_runtime.h>
#include <math.h>

#define PI_F 3.14159265358979323846f

typedef _Float16 h8 __attribute__((ext_vector_type(8)));
typedef float f4 __attribute__((ext_vector_type(4)));

__device__ __forceinline__ float sigm_(float x){ return 1.0f/(1.0f+__expf(-x)); }
__device__ __forceinline__ float silu_(float x){ return x*sigm_(x); }
__device__ __forceinline__ h8 ldh8(const _Float16* p){
    return __builtin_bit_cast(h8, *(const float4*)(p));
}

// B layout (fp16, in d_ws):
//   B1T: per layer [n<112][k<192]  (n<50: Ws col, 50..99: Wg col, 100+: 0)
//   B2T: per layer [n<64][k<192]   (n<50: Wv col, else 0)
//   k segments: [0,50): W_hi(c=k) | [64,114): W_hi(c=k-64) | [128,178): W_lo(c=k-128)
#define B1_PER_L 21504
#define B2_PER_L 12288
#define B1_TOT   129024
#define B_TOT    202752

// ---------------------------------------------------------------------------
// K1 (merged): block 0 = pre[] + output boundary zeros; blocks [1..nTb] =
// spine table (4 entries/block, 1/wave); blocks (nTb..] = fill_B.
// ---------------------------------------------------------------------------
__global__ void precompute_all(const float* __restrict__ W_embed,
                               const float* __restrict__ Wr1,
                               const float* __restrict__ br1,
                               const float* __restrict__ Wr2,
                               const float* __restrict__ Ws,
                               const float* __restrict__ Wg,
                               const float* __restrict__ Wv,
                               float* __restrict__ pre,
                               float* __restrict__ T,
                               int tabN,
                               _Float16* __restrict__ B,
                               float* __restrict__ out,
                               int nTb)
{
    const int bid = blockIdx.x;
    const int tid = threadIdx.x;
    const float wdt = 0.06f / 9.0f;

    if (bid == 0) {
        // ---- zero output boundary rows (t=0, t=513) : 64 batches x 6 floats
        for (int i = tid; i < 384; i += 256) {
            int b = i / 6, r = i - b * 6;
            int t = (r < 3) ? 0 : 513;
            out[((size_t)(b * 514 + t)) * 3 + (r % 3)] = 0.0f;
        }
        // ---- pre[]: s1 trajectory + bar-edge weights (barriers: all 256 thr)
        __shared__ float s1[50];
        __shared__ float hid[64];
        if (tid < 50) s1[tid] = W_embed[tid] + W_embed[50 + tid];
        __syncthreads();

        const float rbar = 0.05f;
        const float fcb = 0.5f * (__cosf(PI_F * (rbar / 0.06f)) + 1.0f);
        float emb[12];
#pragma unroll
        for (int i = 0; i < 10; ++i) {
            float d = (rbar - (float)i * wdt) / wdt;
            emb[i] = __expf(-d * d) * fcb;
        }
        emb[10] = 0.0f; emb[11] = 1.0f;

        for (int l = 0; l < 6; ++l) {
            if (tid < 50) pre[l * 50 + tid] = s1[tid];
            if (tid < 64) {
                float a = br1[l * 64 + tid];
#pragma unroll
                for (int i = 0; i < 12; ++i) a += emb[i] * Wr1[l * 768 + i * 64 + tid];
                hid[tid] = silu_(a);
            }
            __syncthreads();
            for (int m = tid; m < 250; m += 256) {
                float acc = 0.0f;
                for (int j = 0; j < 64; ++j) acc += hid[j] * Wr2[l * 16000 + j * 250 + m];
                pre[300 + l * 250 + m] = acc * fcb;
            }
            float sacc = 0.0f;
            if (tid < 50) {
                for (int c = 0; c < 50; ++c) sacc += s1[c] * Ws[l * 2500 + c * 50 + tid];
            }
            __syncthreads();
            if (tid < 50) s1[tid] = silu_(sacc);
            __syncthreads();
        }
    } else if (bid <= nTb) {
        // ---- spine-edge table entry per wave ----
        const int e = (bid - 1) * 4 + (tid >> 6);
        const int lane = tid & 63;
        const int total = 6 * (tabN + 1);
        if (e >= total) return;
        const int l = e / (tabN + 1);
        const int i = e - l * (tabN + 1);

        float r = (float)i * (0.06f / (float)tabN);
        float t = fminf(r * (1.0f / 0.06f), 1.0f);
        float fc = 0.5f * (__cosf(PI_F * t) + 1.0f);
        float emb[10];
#pragma unroll
        for (int k = 0; k < 10; ++k) {
            float d = (r - (float)k * wdt) / wdt;
            emb[k] = __expf(-d * d) * fc;
        }
        float a = br1[l * 64 + lane] + Wr1[l * 768 + 640 + lane];  // edge_attr [1,0]
#pragma unroll
        for (int k = 0; k < 10; ++k) a += emb[k] * Wr1[l * 768 + k * 64 + lane];
        float hv = silu_(a);

        float acc0 = 0.0f, acc1 = 0.0f;
        const float* wr2 = Wr2 + l * 16000;
        for (int j = 0; j < 64; ++j) {
            float hj = __shfl(hv, j);
            acc0 += hj * wr2[j * 250 + lane];
            acc1 += hj * wr2[j * 250 + 64 + lane];
        }
        float* tp = T + (size_t)e * 100;
        tp[lane] = acc0 * fc;
        if (lane < 36) tp[64 + lane] = acc1 * fc;
    } else {
        // ---- fill_B ----
        int idx = (bid - 1 - nTb) * 256 + tid;
        if (idx >= B_TOT) return;
        int l, n, k, which;
        size_t off;
        if (idx < B1_TOT) {
            l = idx / B1_PER_L; int r = idx - l * B1_PER_L;
            n = r / 192; k = r - n * 192; which = 0;
            off = (size_t)l * B1_PER_L + n * 192 + k;
        } else {
            int j = idx - B1_TOT;
            l = j / B2_PER_L; int r = j - l * B2_PER_L;
            n = r / 192; k = r - n * 192; which = 1;
            off = B1_TOT + (size_t)l * B2_PER_L + n * 192 + k;
        }
        int seg = -1, c = 0;
        if (k < 50)                  { seg = 0; c = k; }
        else if (k >= 64 && k < 114) { seg = 1; c = k - 64; }
        else if (k >= 128 && k < 178){ seg = 2; c = k - 128; }
        _Float16 val = (_Float16)0.0f;
        if (seg >= 0) {
            float w = 0.0f;
            if (which == 0) {
                if (n < 50)       w = Ws[l * 2500 + c * 50 + n];
                else if (n < 100) w = Wg[l * 2500 + c * 50 + (n - 50)];
            } else {
                if (n < 50)       w = Wv[l * 2500 + c * 50 + n];
            }
            _Float16 hi = (_Float16)w;
            val = (seg < 2) ? hi : (_Float16)(w - (float)hi);
        }
        B[off] = val;
    }
}

// ---------------------------------------------------------------------------
// K2: fused forward. Block = 8 windows (2/wave). A rows stride 152 halves
// (76 words, 12 mod 32 -> 2-way free for frag reads). C stored TRANSPOSED
// (outHT[32][100], outQT[80][50]) -> stride-1 conflict-free writes/readback.
// ---------------------------------------------------------------------------
__global__ __launch_bounds__(256, 4)
void fused_main(const float* __restrict__ y,
                const float* __restrict__ W_embed,
                const float* __restrict__ W_out,
                const float* __restrict__ pre,
                const float* __restrict__ T,
                int tabN,
                const _Float16* __restrict__ Bws,
                float* __restrict__ out)
{
    __shared__ __align__(16) char LB[112 * 152 * 2];   // 34048 B
    _Float16* A   = (_Float16*)LB;
    float* outHT  = (float*)LB;          // [32][100]
    float* outQT  = (float*)LB + 3200;   // [80][50]

    const int tid  = threadIdx.x;
    const int wave = tid >> 6;
    const int lane = tid & 63;
    const int kl   = (lane < 50) ? lane : 49;
    const int fm   = lane & 15;
    const int fq   = lane >> 4;

    const _Float16* B1 = Bws;
    const _Float16* B2 = Bws + B1_TOT;

    // ---- per-window geometry ----
    float offx[2], offy[2], u3x_[2], u3y_[2], uspx_[2], uspy_[2], fr_[2];
    int   ti_[2], inr_[2];
#pragma unroll
    for (int w = 0; w < 2; ++w) {
        int wid = blockIdx.x * 8 + wave * 2 + w;
        int b = wid >> 9, tw = wid & 511;
        const float* yb = y + ((size_t)(b * 514 + tw)) * 6;
        float c0x = yb[0], c0y = yb[1];
        float c1x = yb[6], c1y = yb[7], a1 = yb[8];
        float sn, cs; __sincosf(a1, &sn, &cs);
        offx[w] = -0.05f * sn; offy[w] = 0.05f * cs;
        float svx = c0x - c1x, svy = c0y - c1y;
        float r_sp = sqrtf(svx * svx + svy * svy);
        float inv_sp = 1.0f / (r_sp + 1e-12f);
        uspx_[w] = svx * inv_sp; uspy_[w] = svy * inv_sp;
        float rb2 = sqrtf(offx[w] * offx[w] + offy[w] * offy[w]);
        float invb = 1.0f / (rb2 + 1e-12f);
        u3x_[w] = -offx[w] * invb; u3y_[w] = -offy[w] * invb;
        float tp = r_sp * ((float)tabN / 0.06f);
        inr_[w] = tp < (float)tabN;
        int ti = (int)tp;
        if (ti > tabN - 1) ti = tabN - 1;
        if (ti < 0) ti = 0;
        ti_[w] = ti; fr_[w] = tp - (float)ti;
    }

    // ---- initial states ----
    float s3[2], s4[2], s5[2];
    float v3x[2], v3y[2], v3z[2], v4x[2], v4y[2], v4z[2], v5x[2], v5y[2], v5z[2];
    {
        float i35 = W_embed[kl] + W_embed[100 + kl];
        float i4  = W_embed[kl] + W_embed[50 + kl];
#pragma unroll
        for (int w = 0; w < 2; ++w) {
            s3[w] = i35; s5[w] = i35; s4[w] = i4;
            v3x[w] = v3y[w] = v3z[w] = 0.0f;
            v4x[w] = v4y[w] = v4z[w] = 0.0f;
            v5x[w] = v5y[w] = v5z[w] = 0.0f;
        }
    }

    for (int l = 0; l < 6; ++l) {
        __syncthreads();   // overlay region free

        float s1l = pre[l * 50 + kl];
        const float* wbp = pre + 300 + l * 250;
        float wb0 = wbp[kl], wb1 = wbp[50 + kl], wb2 = wbp[100 + kl],
              wb3 = wbp[150 + kl], wb4 = wbp[200 + kl];

        const float THIRD = 1.0f / 3.0f;
#pragma unroll
        for (int w = 0; w < 2; ++w) {
            const float* tb = T + ((size_t)(l * (tabN + 1) + ti_[w])) * 100;
            float t00 = tb[kl], t01 = tb[50 + kl], t10 = tb[100 + kl], t11 = tb[150 + kl];
            float wsp0 = inr_[w] ? (t00 + fr_[w] * (t10 - t00)) : 0.0f;
            float wsp1 = inr_[w] ? (t01 + fr_[w] * (t11 - t01)) : 0.0f;

            float u3x = u3x_[w], u3y = u3y_[w];
            float dot3 = v4x[w] * u3x + v4y[w] * u3y;
            float ms3 = wb0 * s4[w] + wb2 * dot3;
            float ms5 = wb0 * s4[w] - wb2 * dot3;
            float ms4 = wsp0 * s1l;
            float bAx = wb1 * s4[w] * u3x - wb3 * v4z[w] * u3y;
            float bAy = wb1 * s4[w] * u3y + wb3 * v4z[w] * u3x;
            float bBx = wb4 * (dot3 * u3x - v4x[w] * THIRD);
            float bBy = wb4 * (dot3 * u3y - v4y[w] * THIRD);
            float crz = wb3 * (v4x[w] * u3y - v4y[w] * u3x);
            float mzc = -wb4 * v4z[w] * THIRD;

            float vals[12];
            vals[0] = s3[w] + ms3;
            vals[1] = s4[w] + ms4;
            vals[2] = s5[w] + ms5;
            vals[3] = v3x[w] + bAx + bBx;
            vals[4] = v3y[w] + bAy + bBy;
            vals[5] = v3z[w] + crz + mzc;
            vals[6] = v4x[w] + wsp1 * s1l * uspx_[w];
            vals[7] = v4y[w] + wsp1 * s1l * uspy_[w];
            vals[8] = v4z[w];
            vals[9]  = v5x[w] - bAx + bBx;
            vals[10] = v5y[w] - bAy + bBy;
            vals[11] = v5z[w] - crz + mzc;

            int wv = wave * 2 + w;
#pragma unroll
            for (int q = 0; q < 12; ++q) {
                int row = (q < 3) ? (wv * 3 + q) : (32 + wv * 9 + (q - 3));
                float x = (lane < 50) ? vals[q] : 0.0f;
                _Float16 hi = (_Float16)x;
                _Float16 lo = (_Float16)(x - (float)hi);
                A[row * 152 + lane]      = hi;
                A[row * 152 + 64 + lane] = lo;
            }
        }
        // zero pad rows (H 24..31, Q-block rows 104..111)
        {
            int pr  = tid >> 4;
            int row = (pr < 8) ? (24 + pr) : (96 + pr);
            f4 z = {0.0f, 0.0f, 0.0f, 0.0f};
            *(f4*)(A + row * 152 + (tid & 15) * 8) = z;
        }
        __syncthreads();   // A complete

        // ---- MFMA phase ----
        f4 cst[9];
        const _Float16* B1l = B1 + (size_t)l * B1_PER_L;
        const _Float16* B2l = B2 + (size_t)l * B2_PER_L;

        // ji0: H, n-tile = wave (n = wave*16+fm <= 63)
        {
            const _Float16* bp = B1l + (wave * 16 + fm) * 192 + fq * 8;
            h8 b0 = ldh8(bp), b1 = ldh8(bp + 32), b2 = ldh8(bp + 64),
               b3 = ldh8(bp + 96), b4 = ldh8(bp + 128), b5 = ldh8(bp + 160);
#pragma unroll
            for (int mt = 0; mt < 2; ++mt) {
                const _Float16* ap = A + (mt * 16 + fm) * 152 + fq * 8;
                h8 a0 = ldh8(ap), a1 = ldh8(ap + 32), a2 = ldh8(ap + 64), a3 = ldh8(ap + 96);
                f4 acc = {0.0f, 0.0f, 0.0f, 0.0f};
                acc = __builtin_amdgcn_mfma_f32_16x16x32_f16(a0, b0, acc, 0, 0, 0);
                acc = __builtin_amdgcn_mfma_f32_16x16x32_f16(a1, b1, acc, 0, 0, 0);
                acc = __builtin_amdgcn_mfma_f32_16x16x32_f16(a2, b2, acc, 0, 0, 0);
                acc = __builtin_amdgcn_mfma_f32_16x16x32_f16(a3, b3, acc, 0, 0, 0);
                acc = __builtin_amdgcn_mfma_f32_16x16x32_f16(a0, b4, acc, 0, 0, 0);
                acc = __builtin_amdgcn_mfma_f32_16x16x32_f16(a1, b5, acc, 0, 0, 0);
                cst[mt] = acc;
            }
        }
        // ji1: H, n-tile = 4+wave (waves 0..2)
        if (wave < 3) {
            const _Float16* bp = B1l + ((4 + wave) * 16 + fm) * 192 + fq * 8;
            h8 b0 = ldh8(bp), b1 = ldh8(bp + 32), b2 = ldh8(bp + 64),
               b3 = ldh8(bp + 96), b4 = ldh8(bp + 128), b5 = ldh8(bp + 160);
#pragma unroll
            for (int mt = 0; mt < 2; ++mt) {
                const _Float16* ap = A + (mt * 16 + fm) * 152 + fq * 8;
                h8 a0 = ldh8(ap), a1 = ldh8(ap + 32), a2 = ldh8(ap + 64), a3 = ldh8(ap + 96);
                f4 acc = {0.0f, 0.0f, 0.0f, 0.0f};
                acc = __builtin_amdgcn_mfma_f32_16x16x32_f16(a0, b0, acc, 0, 0, 0);
                acc = __builtin_amdgcn_mfma_f32_16x16x32_f16(a1, b1, acc, 0, 0, 0);
                acc = __builtin_amdgcn_mfma_f32_16x16x32_f16(a2, b2, acc, 0, 0, 0);
                acc = __builtin_amdgcn_mfma_f32_16x16x32_f16(a3, b3, acc, 0, 0, 0);
                acc = __builtin_amdgcn_mfma_f32_16x16x32_f16(a0, b4, acc, 0, 0, 0);
                acc = __builtin_amdgcn_mfma_f32_16x16x32_f16(a1, b5, acc, 0, 0, 0);
                cst[2 + mt] = acc;
            }
        }
        // ji2: Q, n-tile = wave
        {
            const _Float16* bp = B2l + (wave * 16 + fm) * 192 + fq * 8;
            h8 b0 = ldh8(bp), b1 = ldh8(bp + 32), b2 = ldh8(bp + 64),
               b3 = ldh8(bp + 96), b4 = ldh8(bp + 128), b5 = ldh8(bp + 160);
#pragma unroll
            for (int mt = 0; mt < 5; ++mt) {
                const _Float16* ap = A + (32 + mt * 16 + fm) * 152 + fq * 8;
                h8 a0 = ldh8(ap), a1 = ldh8(ap + 32), a2 = ldh8(ap + 64), a3 = ldh8(ap + 96);
                f4 acc = {0.0f, 0.0f, 0.0f, 0.0f};
                acc = __builtin_amdgcn_mfma_f32_16x16x32_f16(a0, b0, acc, 0, 0, 0);
                acc = __builtin_amdgcn_mfma_f32_16x16x32_f16(a1, b1, acc, 0, 0, 0);
                acc = __builtin_amdgcn_mfma_f32_16x16x32_f16(a2, b2, acc, 0, 0, 0);
                acc = __builtin_amdgcn_mfma_f32_16x16x32_f16(a3, b3, acc, 0, 0, 0);
                acc = __builtin_amdgcn_mfma_f32_16x16x32_f16(a0, b4, acc, 0, 0, 0);
                acc = __builtin_amdgcn_mfma_f32_16x16x32_f16(a1, b5, acc, 0, 0, 0);
                cst[4 + mt] = acc;
            }
        }
        __syncthreads();   // all A-reads done -> overlay safe

        // ---- C writes, transposed (lanes stride-1 in n: conflict-free) ----
        {
            int n0 = wave * 16 + fm;                     // < 64
#pragma unroll
            for (int mt = 0; mt < 2; ++mt)
#pragma unroll
                for (int i = 0; i < 4; ++i)
                    outHT[(mt * 16 + fq * 4 + i) * 100 + n0] = cst[mt][i];
            if (wave < 3) {
                int n1 = (4 + wave) * 16 + fm;           // 64..111
                if (n1 < 100) {
#pragma unroll
                    for (int mt = 0; mt < 2; ++mt)
#pragma unroll
                        for (int i = 0; i < 4; ++i)
                            outHT[(mt * 16 + fq * 4 + i) * 100 + n1] = cst[2 + mt][i];
                }
            }
            if (n0 < 50) {
#pragma unroll
                for (int mt = 0; mt < 5; ++mt)
#pragma unroll
                    for (int i = 0; i < 4; ++i)
                        outQT[(mt * 16 + fq * 4 + i) * 50 + n0] = cst[4 + mt][i];
            }
        }
        __syncthreads();   // outputs ready

        // ---- readback + activations (stride-1 in kl: conflict-free) ----
#pragma unroll
        for (int w = 0; w < 2; ++w) {
            int wv = wave * 2 + w;
            int mb = wv * 3, qb = wv * 9;
            float as3 = outHT[(mb    ) * 100 + kl];
            float as4 = outHT[(mb + 1) * 100 + kl];
            float as5 = outHT[(mb + 2) * 100 + kl];
            float ag3 = outHT[(mb    ) * 100 + 50 + kl];
            float ag4 = outHT[(mb + 1) * 100 + 50 + kl];
            float ag5 = outHT[(mb + 2) * 100 + 50 + kl];
            float g3 = sigm_(ag3), g4 = sigm_(ag4), g5 = sigm_(ag5);
            s3[w] = silu_(as3); s4[w] = silu_(as4); s5[w] = silu_(as5);
            v3x[w] = outQT[(qb    ) * 50 + kl] * g3;
            v3y[w] = outQT[(qb + 1) * 50 + kl] * g3;
            v3z[w] = outQT[(qb + 2) * 50 + kl] * g3;
            v4x[w] = outQT[(qb + 3) * 50 + kl] * g4;
            v4y[w] = outQT[(qb + 4) * 50 + kl] * g4;
            v4z[w] = outQT[(qb + 5) * 50 + kl] * g4;
            v5x[w] = outQT[(qb + 6) * 50 + kl] * g5;
            v5y[w] = outQT[(qb + 7) * 50 + kl] * g5;
            v5z[w] = outQT[(qb + 8) * 50 + kl] * g5;
        }
    }

    // ---- output epilogue ----
    float wo = (lane < 50) ? W_out[lane] : 0.0f;
#pragma unroll
    for (int w = 0; w < 2; ++w) {
        float px  = (v3x[w] + v4x[w] + v5x[w]) * wo;
        float py  = (v3y[w] + v4y[w] + v5y[w]) * wo;
        float dxv = (v3x[w] - v5x[w]) * wo;
        float dyv = (v3y[w] - v5y[w]) * wo;
#pragma unroll
        for (int o = 32; o > 0; o >>= 1) {
            px  += __shfl_xor(px, o);
            py  += __shfl_xor(py, o);
            dxv += __shfl_xor(dxv, o);
            dyv += __shfl_xor(dyv, o);
        }
        if (lane == 0) {
            int wid = blockIdx.x * 8 + wave * 2 + w;
            int b = wid >> 9, tw = wid & 511;
            float* op = out + ((size_t)(b * 514 + (tw + 1))) * 3;
            op[0] = px;
            op[1] = py;
            op[2] = offx[w] * dyv - offy[w] * dxv;
        }
    }
}

// ---------------------------------------------------------------------------
extern "C" void kernel_launch(void* const* d_in, const int* in_sizes, int n_in,
                              void* d_out, int out_size, void* d_ws, size_t ws_size,
                              hipStream_t stream) {
    const float* y       = (const float*)d_in[0];
    const float* W_embed = (const float*)d_in[1];
    const float* Wr1     = (const float*)d_in[2];
    const float* br1     = (const float*)d_in[3];
    const float* Wr2     = (const float*)d_in[4];
    const float* Ws      = (const float*)d_in[5];
    const float* Wv      = (const float*)d_in[6];
    const float* Wg      = (const float*)d_in[7];
    const float* W_out   = (const float*)d_in[8];
    float* out = (float*)d_out;

    _Float16* Bws = (_Float16*)d_ws;                         // 405504 B
    float* pre = (float*)((char*)d_ws + B_TOT * 2);          // 1800 floats
    float* T   = pre + 1800;

    int tabN = 2048;
    while (tabN > 64 &&
           (size_t)B_TOT * 2 + (size_t)(1800 + 6 * (tabN + 1) * 100) * sizeof(float) > ws_size)
        tabN >>= 1;

    int nTb = (6 * (tabN + 1) + 3) / 4;
    int nFb = (B_TOT + 255) / 256;
    precompute_all<<<1 + nTb + nFb, 256, 0, stream>>>(
        W_embed, Wr1, br1, Wr2, Ws, Wg, Wv, pre, T, tabN, Bws, out, nTb);
    fused_main<<<4096, 256, 0, stream>>>(y, W_embed, W_out, pre, T, tabN, Bws, out);
}